// Round 2
// baseline (403.574 us; speedup 1.0000x reference)
//
#include <hip/hip_runtime.h>

// DynamicWeightedLoss: weighted CE (CCL-area dynamic weights) + dice + focal.
// B=16, C=4, H=W=512. Output: 1 float.

namespace {
constexpr int IMG_W = 512;
constexpr int IMG_H = 512;
constexpr int NB    = 16;
constexpr int NC    = 4;
constexpr int HW    = IMG_H * IMG_W;   // 262144 = 2^18
constexpr int NPIX  = NB * HW;         // 4194304
constexpr float ALPHA  = 1.0f;
constexpr float BETA   = 0.7f;
constexpr float UPPER  = 1000.0f;
constexpr float LOWER  = 200.0f;
constexpr float W_UP   = 2.5f;
constexpr float W_LO   = 20.0f;
constexpr float SMOOTH = 1.0f;
// acc layout (doubles): [0]=wce_sum [1]=focal_sum [2..66)=psum[b][c]
// [66..130)=inter[b][c] [130..194)=cnt[b][c]
constexpr int ACC_WCE   = 0;
constexpr int ACC_FOCAL = 1;
constexpr int ACC_PSUM  = 2;
constexpr int ACC_INTER = 66;
constexpr int ACC_CNT   = 130;
constexpr int ACC_N     = 256;  // round up
}

__device__ __forceinline__ int ld_parent(int* parent, int i) {
    // device-scope coherent read (per-XCD L2s are not coherent)
    return __hip_atomic_load(&parent[i], __ATOMIC_RELAXED, __HIP_MEMORY_SCOPE_AGENT);
}

__device__ __forceinline__ int find_root(int* parent, int x) {
    int p = ld_parent(parent, x);
    while (p != x) { x = p; p = ld_parent(parent, x); }
    return x;
}

__device__ __forceinline__ void unite(int* parent, int a, int b) {
    int ra = find_root(parent, a);
    int rb = find_root(parent, b);
    while (ra != rb) {
        int lo = ra < rb ? ra : rb;
        int hi = ra < rb ? rb : ra;
        int old = atomicCAS(&parent[hi], hi, lo);
        if (old == hi) return;
        ra = find_root(parent, old);
        rb = find_root(parent, lo);
    }
}

__global__ void init_kernel(int* __restrict__ parent, int* __restrict__ counts,
                            double* __restrict__ acc) {
    int gi = blockIdx.x * blockDim.x + threadIdx.x;
    if (gi < NPIX) { parent[gi] = gi; counts[gi] = 0; }
    if (gi < ACC_N) acc[gi] = 0.0;
}

__global__ void union_kernel(const int* __restrict__ tgt, int* parent) {
    int gi = blockIdx.x * blockDim.x + threadIdx.x;
    if (gi >= NPIX) return;
    if (tgt[gi] != 2) return;
    int p = gi & (HW - 1);
    int w = p & (IMG_W - 1);
    int h = p >> 9;  // /512 within image
    if (w + 1 < IMG_W && tgt[gi + 1] == 2) unite(parent, gi, gi + 1);
    if (h + 1 < IMG_H && tgt[gi + IMG_W] == 2) unite(parent, gi, gi + IMG_W);
}

__global__ void flatten_count_kernel(const int* __restrict__ tgt, int* parent,
                                     int* counts) {
    int gi = blockIdx.x * blockDim.x + threadIdx.x;
    if (gi >= NPIX) return;
    if (tgt[gi] != 2) return;
    int r = find_root(parent, gi);
    parent[gi] = r;
    atomicAdd(&counts[r], 1);
}

__device__ __forceinline__ float wave_reduce(float v) {
    #pragma unroll
    for (int off = 32; off > 0; off >>= 1) v += __shfl_down(v, off);
    return v;
}

__global__ void __launch_bounds__(256)
loss_kernel(const float* __restrict__ logits, const float* __restrict__ cw,
            const int* __restrict__ tgt, const int* __restrict__ parent,
            const int* __restrict__ counts, double* __restrict__ acc) {
    int gi = blockIdx.x * blockDim.x + threadIdx.x;
    int b  = gi >> 18;          // / HW
    int p  = gi & (HW - 1);
    const float* base = logits + (size_t)b * NC * HW + p;
    float x0 = base[0];
    float x1 = base[HW];
    float x2 = base[2 * HW];
    float x3 = base[3 * HW];
    float m  = fmaxf(fmaxf(x0, x1), fmaxf(x2, x3));
    float e0 = expf(x0 - m), e1 = expf(x1 - m), e2 = expf(x2 - m), e3 = expf(x3 - m);
    float S  = e0 + e1 + e2 + e3;
    float invS = 1.0f / S;
    int   t  = tgt[gi];
    float xt = (t == 0) ? x0 : (t == 1) ? x1 : (t == 2) ? x2 : x3;
    float nll = logf(S) + m - xt;           // -log_softmax[t]
    float ce  = cw[t] * nll;
    float pt  = expf(-ce);
    float omp = 1.0f - pt;
    float focal_i = ALPHA * omp * omp * ce; // GAMMA = 2
    float dyn = 1.0f;
    if (t == 2) {
        float area = (float)counts[parent[gi]];
        float rw;
        if (area > UPPER)      rw = W_UP;
        else if (area < LOWER) rw = W_LO;
        else rw = W_UP + (W_LO - W_UP) * (UPPER - area) / (UPPER - LOWER);
        dyn = rw;
    }
    float pr0 = e0 * invS, pr1 = e1 * invS, pr2 = e2 * invS, pr3 = e3 * invS;
    float prt = (t == 0) ? pr0 : (t == 1) ? pr1 : (t == 2) ? pr2 : pr3;

    float vals[14];
    vals[0] = ce * dyn;
    vals[1] = focal_i;
    vals[2] = pr0; vals[3] = pr1; vals[4] = pr2; vals[5] = pr3;
    vals[6] = (t == 0) ? prt : 0.0f;
    vals[7] = (t == 1) ? prt : 0.0f;
    vals[8] = (t == 2) ? prt : 0.0f;
    vals[9] = (t == 3) ? prt : 0.0f;
    vals[10] = (t == 0) ? 1.0f : 0.0f;
    vals[11] = (t == 1) ? 1.0f : 0.0f;
    vals[12] = (t == 2) ? 1.0f : 0.0f;
    vals[13] = (t == 3) ? 1.0f : 0.0f;

    __shared__ float red[14][4];
    int lane = threadIdx.x & 63;
    int wv   = threadIdx.x >> 6;
    #pragma unroll
    for (int i = 0; i < 14; ++i) {
        float v = wave_reduce(vals[i]);
        if (lane == 0) red[i][wv] = v;
    }
    __syncthreads();
    if (threadIdx.x < 14) {
        int i = threadIdx.x;
        float s = red[i][0] + red[i][1] + red[i][2] + red[i][3];
        double* dst;
        if (i == 0)      dst = &acc[ACC_WCE];
        else if (i == 1) dst = &acc[ACC_FOCAL];
        else if (i < 6)  dst = &acc[ACC_PSUM  + b * NC + (i - 2)];
        else if (i < 10) dst = &acc[ACC_INTER + b * NC + (i - 6)];
        else             dst = &acc[ACC_CNT   + b * NC + (i - 10)];
        atomicAdd(dst, (double)s);
    }
}

__global__ void final_kernel(const double* __restrict__ acc, float* __restrict__ out) {
    int i = threadIdx.x;  // 0..63 -> (b,c)
    double psum  = acc[ACC_PSUM + i];
    double inter = acc[ACC_INTER + i];
    double cnt   = acc[ACC_CNT + i];
    double dice  = (2.0 * inter + (double)SMOOTH) / (psum + cnt + (double)SMOOTH);
    #pragma unroll
    for (int off = 32; off > 0; off >>= 1) dice += __shfl_down(dice, off);
    if (i == 0) {
        double dice_mean = dice / (double)(NB * NC);
        double wce   = acc[ACC_WCE]   / (double)NPIX;
        double focal = acc[ACC_FOCAL] / (double)NPIX;
        double loss = (double)BETA * wce + (1.0 - (double)BETA) * (1.0 - dice_mean)
                    + focal;
        out[0] = (float)loss;
    }
}

extern "C" void kernel_launch(void* const* d_in, const int* in_sizes, int n_in,
                              void* d_out, int out_size, void* d_ws, size_t ws_size,
                              hipStream_t stream) {
    const float* logits = (const float*)d_in[0];
    const float* cw     = (const float*)d_in[1];
    const int*   tgt    = (const int*)d_in[2];
    float*       out    = (float*)d_out;
    char*        ws     = (char*)d_ws;
    int*    parent = (int*)ws;
    int*    counts = (int*)(ws + (size_t)NPIX * 4);
    double* acc    = (double*)(ws + (size_t)NPIX * 8);

    const int nb = NPIX / 256;
    hipLaunchKernelGGL(init_kernel, dim3(nb), dim3(256), 0, stream, parent, counts, acc);
    hipLaunchKernelGGL(union_kernel, dim3(nb), dim3(256), 0, stream, tgt, parent);
    hipLaunchKernelGGL(flatten_count_kernel, dim3(nb), dim3(256), 0, stream, tgt, parent, counts);
    hipLaunchKernelGGL(loss_kernel, dim3(nb), dim3(256), 0, stream,
                       logits, cw, tgt, parent, counts, acc);
    hipLaunchKernelGGL(final_kernel, dim3(1), dim3(64), 0, stream, acc, out);
}

// Round 3
// 211.917 us; speedup vs baseline: 1.9044x; 1.9044x over previous
//
#include <hip/hip_runtime.h>

// DynamicWeightedLoss: weighted CE (CCL-area dynamic weights) + dice + focal.
// B=16, C=4, H=W=512. Output: 1 float.
// ws layout: parent[NPIX] int | counts[NPIX] int | partials[1024*16] float

namespace {
constexpr int IMG_W = 512;
constexpr int IMG_H = 512;
constexpr int NB    = 16;
constexpr int NC    = 4;
constexpr int HW    = IMG_H * IMG_W;   // 262144 = 2^18
constexpr int NPIX  = NB * HW;         // 4194304
constexpr float ALPHA  = 1.0f;
constexpr float BETA   = 0.7f;
constexpr float UPPER  = 1000.0f;
constexpr float LOWER  = 200.0f;
constexpr float W_UP   = 2.5f;
constexpr float W_LO   = 20.0f;
constexpr float SMOOTH = 1.0f;
constexpr int LOSS_BLOCKS_PER_IMG = 64;           // 4096 px per block
constexpr int LOSS_BLOCKS = NB * LOSS_BLOCKS_PER_IMG;  // 1024
constexpr int PART_STRIDE = 16;                   // 14 used, padded
// partial slot order: 0=wce 1=focal 2..5=psum[c] 6..9=inter[c] 10..13=cnt[c]
}

__device__ __forceinline__ int ld_parent(int* parent, int i) {
    return __hip_atomic_load(&parent[i], __ATOMIC_RELAXED, __HIP_MEMORY_SCOPE_AGENT);
}

__device__ __forceinline__ int find_root_atomic(int* parent, int x) {
    int p = ld_parent(parent, x);
    while (p != x) { x = p; p = ld_parent(parent, x); }
    return x;
}

__device__ __forceinline__ void unite(int* parent, int a, int b) {
    int ra = find_root_atomic(parent, a);
    int rb = find_root_atomic(parent, b);
    while (ra != rb) {
        int lo = ra < rb ? ra : rb;
        int hi = ra < rb ? rb : ra;
        int old = atomicCAS(&parent[hi], hi, lo);
        if (old == hi) return;
        ra = find_root_atomic(parent, old);
        rb = find_root_atomic(parent, lo);
    }
}

// 1 thread/pixel. Horizontal run-linking via wave ballot: parent = run start.
// Rows (512 px) are a multiple of wave width (64) so runs never cross rows
// within a wave; cross-wave-boundary runs are merged in union_kernel.
__global__ void __launch_bounds__(256)
init_kernel(const int* __restrict__ tgt, int* __restrict__ parent,
            int* __restrict__ counts) {
    int gi = blockIdx.x * 256 + threadIdx.x;
    int lane = threadIdx.x & 63;
    bool mask = (tgt[gi] == 2);
    unsigned long long bal = __ballot(mask);
    int par = gi;
    if (mask) {
        unsigned long long below = (lane == 0) ? 0ull
                                 : ((1ull << lane) - 1ull);
        unsigned long long zb = (~bal) & below;   // zero bits strictly below lane
        int runstart_lane = (zb == 0ull) ? 0 : (64 - __clzll(zb));
        par = gi - lane + runstart_lane;
    }
    parent[gi] = par;
    counts[gi] = 0;
}

// 4 px/thread: vertical unions + rare cross-wave-boundary horizontal unions.
__global__ void __launch_bounds__(256)
union_kernel(const int* __restrict__ tgt, int* parent) {
    int base = (blockIdx.x * 256 + threadIdx.x) * 4;
    int4 t4 = *reinterpret_cast<const int4*>(&tgt[base]);
    int t[4] = {t4.x, t4.y, t4.z, t4.w};
    bool any = (t[0] == 2) | (t[1] == 2) | (t[2] == 2) | (t[3] == 2);
    if (!any) return;
    int p = base & (HW - 1);
    int h = p >> 9;                      // row within image
    if (h > 0) {
        int4 u4 = *reinterpret_cast<const int4*>(&tgt[base - IMG_W]);
        int u[4] = {u4.x, u4.y, u4.z, u4.w};
        #pragma unroll
        for (int j = 0; j < 4; ++j)
            if (t[j] == 2 && u[j] == 2) unite(parent, base + j, base + j - IMG_W);
    }
    // horizontal union across wave boundary (col % 64 == 0, col > 0)
    if (t[0] == 2 && (base & 63) == 0 && (base & (IMG_W - 1)) != 0) {
        if (tgt[base - 1] == 2) unite(parent, base, base - 1);
    }
}

// 4 px/thread: path-flatten to final root + area counting.
__global__ void __launch_bounds__(256)
flatten_count_kernel(const int* __restrict__ tgt, int* parent, int* counts) {
    int base = (blockIdx.x * 256 + threadIdx.x) * 4;
    int4 t4 = *reinterpret_cast<const int4*>(&tgt[base]);
    int t[4] = {t4.x, t4.y, t4.z, t4.w};
    #pragma unroll
    for (int j = 0; j < 4; ++j) {
        if (t[j] == 2) {
            int x = base + j;
            int pp = parent[x];
            while (pp != x) { x = pp; pp = parent[x]; }
            parent[base + j] = x;
            atomicAdd(&counts[x], 1);
        }
    }
}

__device__ __forceinline__ float wave_reduce(float v) {
    #pragma unroll
    for (int off = 32; off > 0; off >>= 1) v += __shfl_down(v, off);
    return v;
}

// 64 blocks per image, 256 threads, 16 px/thread in registers. No atomics.
__global__ void __launch_bounds__(256)
loss_kernel(const float* __restrict__ logits, const float* __restrict__ cw,
            const int* __restrict__ tgt, const int* __restrict__ parent,
            const int* __restrict__ counts, float* __restrict__ partials) {
    int b    = blockIdx.x >> 6;
    int slab = blockIdx.x & 63;
    const float* Lb = logits + (size_t)b * NC * HW;
    const int*   Tb = tgt + (size_t)b * HW;
    const int*   Pb = parent + (size_t)b * HW;   // roots are global indices
    float cw0 = cw[0], cw1 = cw[1], cw2 = cw[2], cw3 = cw[3];

    float a_wce = 0.f, a_foc = 0.f;
    float a_ps[4] = {0.f, 0.f, 0.f, 0.f};
    float a_in[4] = {0.f, 0.f, 0.f, 0.f};
    float a_ct[4] = {0.f, 0.f, 0.f, 0.f};

    #pragma unroll
    for (int it = 0; it < 4; ++it) {
        int p = slab * 4096 + (it * 256 + threadIdx.x) * 4;
        int4 t4 = *reinterpret_cast<const int4*>(&Tb[p]);
        int tj[4] = {t4.x, t4.y, t4.z, t4.w};
        float4 x0 = *reinterpret_cast<const float4*>(&Lb[p]);
        float4 x1 = *reinterpret_cast<const float4*>(&Lb[p + HW]);
        float4 x2 = *reinterpret_cast<const float4*>(&Lb[p + 2 * HW]);
        float4 x3 = *reinterpret_cast<const float4*>(&Lb[p + 3 * HW]);
        float c0[4] = {x0.x, x0.y, x0.z, x0.w};
        float c1[4] = {x1.x, x1.y, x1.z, x1.w};
        float c2[4] = {x2.x, x2.y, x2.z, x2.w};
        float c3[4] = {x3.x, x3.y, x3.z, x3.w};
        #pragma unroll
        for (int j = 0; j < 4; ++j) {
            float v0 = c0[j], v1 = c1[j], v2 = c2[j], v3 = c3[j];
            int   t  = tj[j];
            float m  = fmaxf(fmaxf(v0, v1), fmaxf(v2, v3));
            float e0 = __expf(v0 - m), e1 = __expf(v1 - m);
            float e2 = __expf(v2 - m), e3 = __expf(v3 - m);
            float S  = e0 + e1 + e2 + e3;
            float invS = __frcp_rn(S);
            float xt = (t == 0) ? v0 : (t == 1) ? v1 : (t == 2) ? v2 : v3;
            float wt = (t == 0) ? cw0 : (t == 1) ? cw1 : (t == 2) ? cw2 : cw3;
            float nll = __logf(S) + m - xt;
            float ce  = wt * nll;
            float pt  = __expf(-ce);
            float omp = 1.0f - pt;
            float focal_i = ALPHA * omp * omp * ce;
            float dyn = 1.0f;
            if (t == 2) {
                float area = (float)counts[Pb[p + j]];
                float interp = W_UP + (W_LO - W_UP) * (UPPER - area) * (1.0f / (UPPER - LOWER));
                float rw = (area > UPPER) ? W_UP : (area < LOWER) ? W_LO : interp;
                dyn = rw;
            }
            float pr0 = e0 * invS, pr1 = e1 * invS, pr2 = e2 * invS, pr3 = e3 * invS;
            float prt = (t == 0) ? pr0 : (t == 1) ? pr1 : (t == 2) ? pr2 : pr3;
            a_wce += ce * dyn;
            a_foc += focal_i;
            a_ps[0] += pr0; a_ps[1] += pr1; a_ps[2] += pr2; a_ps[3] += pr3;
            a_in[t] += prt;
            a_ct[t] += 1.0f;
        }
    }

    float vals[14];
    vals[0] = a_wce; vals[1] = a_foc;
    vals[2] = a_ps[0]; vals[3] = a_ps[1]; vals[4] = a_ps[2]; vals[5] = a_ps[3];
    vals[6] = a_in[0]; vals[7] = a_in[1]; vals[8] = a_in[2]; vals[9] = a_in[3];
    vals[10] = a_ct[0]; vals[11] = a_ct[1]; vals[12] = a_ct[2]; vals[13] = a_ct[3];

    __shared__ float red[14][4];
    int lane = threadIdx.x & 63;
    int wv   = threadIdx.x >> 6;
    #pragma unroll
    for (int i = 0; i < 14; ++i) {
        float v = wave_reduce(vals[i]);
        if (lane == 0) red[i][wv] = v;
    }
    __syncthreads();
    if (threadIdx.x < 14) {
        int i = threadIdx.x;
        partials[blockIdx.x * PART_STRIDE + i] =
            red[i][0] + red[i][1] + red[i][2] + red[i][3];
    }
}

// 1 block, 1024 threads = 16 waves; wave w reduces the 64 partial-blocks of
// image w (loss blocks are contiguous per image).
__global__ void __launch_bounds__(1024)
final_kernel(const float* __restrict__ partials, float* __restrict__ out) {
    int j = threadIdx.x;           // partial-block index 0..1023
    int lane = j & 63;
    int w = j >> 6;                // image index
    float v[14];
    #pragma unroll
    for (int i = 0; i < 14; ++i) v[i] = partials[j * PART_STRIDE + i];
    #pragma unroll
    for (int i = 0; i < 14; ++i) v[i] = wave_reduce(v[i]);

    __shared__ double s_wce[16], s_foc[16], s_dice[16];
    if (lane == 0) {
        double dsum = 0.0;
        #pragma unroll
        for (int c = 0; c < 4; ++c) {
            double inter = v[6 + c], psum = v[2 + c], cnt = v[10 + c];
            dsum += (2.0 * inter + (double)SMOOTH) / (psum + cnt + (double)SMOOTH);
        }
        s_wce[w] = v[0]; s_foc[w] = v[1]; s_dice[w] = dsum;
    }
    __syncthreads();
    if (j == 0) {
        double wce = 0.0, foc = 0.0, dice = 0.0;
        for (int i = 0; i < 16; ++i) { wce += s_wce[i]; foc += s_foc[i]; dice += s_dice[i]; }
        double dice_mean = dice / (double)(NB * NC);
        double wce_mean  = wce / (double)NPIX;
        double foc_mean  = foc / (double)NPIX;
        out[0] = (float)((double)BETA * wce_mean
                         + (1.0 - (double)BETA) * (1.0 - dice_mean) + foc_mean);
    }
}

extern "C" void kernel_launch(void* const* d_in, const int* in_sizes, int n_in,
                              void* d_out, int out_size, void* d_ws, size_t ws_size,
                              hipStream_t stream) {
    const float* logits = (const float*)d_in[0];
    const float* cw     = (const float*)d_in[1];
    const int*   tgt    = (const int*)d_in[2];
    float*       out    = (float*)d_out;
    char*        ws     = (char*)d_ws;
    int*    parent   = (int*)ws;
    int*    counts   = (int*)(ws + (size_t)NPIX * 4);
    float*  partials = (float*)(ws + (size_t)NPIX * 8);

    hipLaunchKernelGGL(init_kernel, dim3(NPIX / 256), dim3(256), 0, stream,
                       tgt, parent, counts);
    hipLaunchKernelGGL(union_kernel, dim3(NPIX / 1024), dim3(256), 0, stream,
                       tgt, parent);
    hipLaunchKernelGGL(flatten_count_kernel, dim3(NPIX / 1024), dim3(256), 0, stream,
                       tgt, parent, counts);
    hipLaunchKernelGGL(loss_kernel, dim3(LOSS_BLOCKS), dim3(256), 0, stream,
                       logits, cw, tgt, parent, counts, partials);
    hipLaunchKernelGGL(final_kernel, dim3(1), dim3(1024), 0, stream,
                       partials, out);
}